// Round 7
// baseline (182.681 us; speedup 1.0000x reference)
//
#include <hip/hip_runtime.h>

constexpr int Bn = 4, NL = 1024, HWn = 4096, NH = 8;

typedef __attribute__((ext_vector_type(8))) short bf16x8;
typedef __attribute__((ext_vector_type(4))) float f32x4;
#define MFMA16 __builtin_amdgcn_mfma_f32_16x16x32_bf16

extern "C" __device__ float __ocml_native_exp2_f32(float);

__device__ __forceinline__ float b2f(unsigned short u) {
  union { unsigned int i; float f; } x; x.i = ((unsigned int)u) << 16; return x.f;
}
__device__ __forceinline__ unsigned short f2b(float f) {
  union { float f; unsigned int i; } x; x.f = f;
  unsigned int r = x.i + 0x7fffu + ((x.i >> 16) & 1u);   // RNE
  return (unsigned short)(r >> 16);
}

// async global->LDS DMA, 16B per lane; LDS dst = readfirstlane(l) + lane*16
__device__ __forceinline__ void async_load16(const unsigned short* g, unsigned short* l) {
  __builtin_amdgcn_global_load_lds(
      (const __attribute__((address_space(1))) unsigned int*)g,
      (__attribute__((address_space(3))) unsigned int*)l, 16, 0, 0);
}

// ---------- ALL input conversions + stats-buffer zeroing in one launch ----------
__global__ __launch_bounds__(256) void convall(const float* __restrict__ x,
    const float* __restrict__ l,
    const float* __restrict__ Wk, const float* __restrict__ Wv,
    const float* __restrict__ Wq, const float* __restrict__ Ww,
    unsigned short* __restrict__ xbf, unsigned short* __restrict__ lbf,
    unsigned short* __restrict__ wkb, unsigned short* __restrict__ wvb,
    unsigned short* __restrict__ wqb,
    unsigned short* __restrict__ wwh, unsigned short* __restrict__ wwl,
    float* __restrict__ Fz)
{
  const int id = blockIdx.x, tid = threadIdx.x;
  if (id < 8192) {
    int i = (id * 256 + tid) * 4;
    float4 v = *(const float4*)(x + i);
    ushort4 o; o.x = f2b(v.x); o.y = f2b(v.y); o.z = f2b(v.z); o.w = f2b(v.w);
    *(ushort4*)(xbf + i) = o;
  } else if (id < 10240) {
    int i = ((id - 8192) * 256 + tid) * 4;
    float4 v = *(const float4*)(l + i);
    ushort4 o; o.x = f2b(v.x); o.y = f2b(v.y); o.z = f2b(v.z); o.w = f2b(v.w);
    *(ushort4*)(lbf + i) = o;
  } else if (id < 10752) {
    int sub = id - 10240;
    int y = sub >> 7, bx = sub & 127;
    int i = (bx * 256 + tid) * 4;
    if (y == 3) {
      if (i >= 65536) return;
      float4 v = *(const float4*)(Ww + i);
      ushort4 hi, lo;
      hi.x = f2b(v.x); lo.x = f2b(v.x - b2f(hi.x));
      hi.y = f2b(v.y); lo.y = f2b(v.y - b2f(hi.y));
      hi.z = f2b(v.z); lo.z = f2b(v.z - b2f(hi.z));
      hi.w = f2b(v.w); lo.w = f2b(v.w - b2f(hi.w));
      *(ushort4*)(wwh + i) = hi;
      *(ushort4*)(wwl + i) = lo;
      return;
    }
    const float* src = y == 0 ? Wk : (y == 1 ? Wv : Wq);
    unsigned short* dst = y == 0 ? wkb : (y == 1 ? wvb : wqb);
    float4 v = *(const float4*)(src + i);
    ushort4 o; o.x = f2b(v.x); o.y = f2b(v.y); o.z = f2b(v.z); o.w = f2b(v.w);
    *(ushort4*)(dst + i) = o;
  } else {
    int i = (id - 10752) * 1024 + tid * 4;
    *(float4*)(Fz + i) = (float4){0.f, 0.f, 0.f, 0.f};
  }
}

// ---------- unified 128x128 MFMA GEMM, K=512, dbuf LDS + global_load_lds ----------
// V-mode: vfrag-layout store staged through LDS -> coalesced bf16x8 stores.
// K-stats / V-colsum fusion unchanged. (R6 form — measured keeper.)
__global__ __launch_bounds__(256, 3) void gemm128(
    const unsigned short* __restrict__ xbf, const unsigned short* __restrict__ lbf,
    const unsigned short* __restrict__ wkb, const unsigned short* __restrict__ wvb,
    const unsigned short* __restrict__ wqb,
    const float* __restrict__ bk, const float* __restrict__ bv, const float* __restrict__ bq,
    unsigned short* __restrict__ khb, unsigned short* __restrict__ vfrag,
    unsigned short* __restrict__ qbuf,
    float* __restrict__ ksum, float* __restrict__ kss, float* __restrict__ vcs)
{
  __shared__ unsigned short sh[16384];        // As[2][4096] | Bs[2][4096]; reused as V-stage
  unsigned short* As0 = sh;
  unsigned short* Bs0 = sh + 8192;
  const int id = blockIdx.x;
  const int mode = id < 256 ? 0 : (id < 512 ? 1 : 2);   // 0=K 1=V 2=Q
  const int local = id - (mode == 0 ? 0 : (mode == 1 ? 256 : 512));
  const int rb = local >> 1, cb = local & 1;
  const int m0 = rb * 128, n0 = cb * 128;
  const unsigned short* A = (mode == 2) ? lbf : xbf;
  const unsigned short* W = (mode == 0) ? wkb : (mode == 1 ? wvb : wqb);
  const float* bias = (mode == 0) ? bk : (mode == 1 ? bv : bq);

  const int tid = threadIdx.x, w = tid >> 6, lane = tid & 63;
  const int quad = lane >> 4, l15 = lane & 15;
  const int wr = w >> 1, wc = w & 1;

  const int p0 = tid, p1 = tid + 256;
  const int am0 = p0 >> 2, ak0 = (p0 & 3) * 8;
  const int am1 = p1 >> 2, ak1 = (p1 & 3) * 8;

  f32x4 acc[4][4];
#pragma unroll
  for (int i = 0; i < 4; ++i)
#pragma unroll
    for (int j = 0; j < 4; ++j) acc[i][j] = (f32x4){0.f, 0.f, 0.f, 0.f};

  // prologue: async-stage kt=0 into buf 0
  async_load16(A + (size_t)(m0 + am0) * 512 + ak0, &As0[p0 * 8]);
  async_load16(A + (size_t)(m0 + am1) * 512 + ak1, &As0[p1 * 8]);
  async_load16(W + (size_t)(n0 + am0) * 512 + ak0, &Bs0[p0 * 8]);
  async_load16(W + (size_t)(n0 + am1) * 512 + ak1, &Bs0[p1 * 8]);

  for (int kt = 0; kt < 16; ++kt) {
    const int cur = kt & 1;
    __syncthreads();                       // buf[cur] DMA complete (vmcnt drained)
    if (kt < 15) {                         // prefetch kt+1 into the other buffer
      int k0 = (kt + 1) * 32;
      int nx = (cur ^ 1) * 4096;
      async_load16(A + (size_t)(m0 + am0) * 512 + k0 + ak0, &As0[nx + p0 * 8]);
      async_load16(A + (size_t)(m0 + am1) * 512 + k0 + ak1, &As0[nx + p1 * 8]);
      async_load16(W + (size_t)(n0 + am0) * 512 + k0 + ak0, &Bs0[nx + p0 * 8]);
      async_load16(W + (size_t)(n0 + am1) * 512 + k0 + ak1, &Bs0[nx + p1 * 8]);
    }
    bf16x8 af[4], bf[4];
#pragma unroll
    for (int fr = 0; fr < 4; ++fr)
      af[fr] = *(const bf16x8*)&As0[cur * 4096 + (wr * 64 + fr * 16 + l15) * 32 + quad * 8];
#pragma unroll
    for (int fc = 0; fc < 4; ++fc)
      bf[fc] = *(const bf16x8*)&Bs0[cur * 4096 + (wc * 64 + fc * 16 + l15) * 32 + quad * 8];
#pragma unroll
    for (int fr = 0; fr < 4; ++fr)
#pragma unroll
      for (int fc = 0; fc < 4; ++fc)
        acc[fr][fc] = MFMA16(af[fr], bf[fc], acc[fr][fc], 0, 0, 0);
  }

  float bb[4];
#pragma unroll
  for (int fc = 0; fc < 4; ++fc) bb[fc] = bias[n0 + wc * 64 + fc * 16 + l15];

  // fused K/V instance-norm & colsum stats (f32 pre-round; error ~1e-5 rel)
  if (mode != 2) {
    const int b = m0 >> 12;
    const int seg = (m0 & 4095) >> 9;
#pragma unroll
    for (int fc = 0; fc < 4; ++fc) {
      float s = 0.f, ssq = 0.f;
#pragma unroll
      for (int fr = 0; fr < 4; ++fr)
#pragma unroll
        for (int r = 0; r < 4; ++r) {
          float v = acc[fr][fc][r] + bb[fc];
          s += v; ssq += v * v;
        }
      s += __shfl_xor(s, 16); s += __shfl_xor(s, 32);
      if (mode == 0) {
        ssq += __shfl_xor(ssq, 16); ssq += __shfl_xor(ssq, 32);
        if (quad == 0) {
          int col = n0 + wc * 64 + fc * 16 + l15;
          atomicAdd(&ksum[b * 256 + col], s);
          atomicAdd(&kss[b * 256 + col], ssq);
        }
      } else if (quad == 0) {
        int col = n0 + wc * 64 + fc * 16 + l15;
        atomicAdd(&vcs[seg * 1024 + b * 256 + col], s);
      }
    }
  }

  if (mode == 1) {
    // stage block's V-tile in LDS (vfrag-local layout), then coalesced stores
    __syncthreads();                       // all waves done reading As/Bs
#pragma unroll
    for (int fc = 0; fc < 4; ++fc) {
      const int ls = wr * 4 + wc * 2 + ((fc * 16 + l15) >> 5);
      const int dvt = fc & 1;
#pragma unroll
      for (int fr = 0; fr < 4; ++fr) {
#pragma unroll
        for (int r = 0; r < 4; ++r) {
          int kappa = 4 * (quad * 4 + r) + fr;
          int kh2 = kappa >> 5, lq = (kappa >> 3) & 3, j = kappa & 7;
          sh[ls * 2048 + kh2 * 1024 + dvt * 512 + lq * 128 + l15 * 8 + j] =
              f2b(acc[fr][fc][r] + bb[fc]);
        }
      }
    }
    __syncthreads();
    const int b2 = m0 >> 12, h0 = cb * 4, seg64b = (m0 & 4095) >> 6;
#pragma unroll
    for (int i = 0; i < 8; ++i) {
      int p = i * 256 + tid;
      int ls = p >> 8, off8 = (p & 255) * 8;
      int dh = ls & 3, wr2 = ls >> 2;
      size_t dst = ((size_t)((b2 * 8 + h0 + dh) * 64) + seg64b + wr2) * 2048 + off8;
      *(bf16x8*)(vfrag + dst) = *(const bf16x8*)&sh[ls * 2048 + off8];
    }
  } else {
    unsigned short* dst = (mode == 0) ? khb : qbuf;
#pragma unroll
    for (int fr = 0; fr < 4; ++fr) {
#pragma unroll
      for (int fc = 0; fc < 4; ++fc) {
        int col = n0 + wc * 64 + fc * 16 + l15;
#pragma unroll
        for (int r = 0; r < 4; ++r) {
          int row = m0 + wr * 64 + fr * 16 + quad * 4 + r;
          unsigned short val = f2b(acc[fr][fc][r] + bb[fc]);
          if (mode == 2) {
            dst[(size_t)row * 256 + col] = val;
          } else {
            int b = row >> 12, n = row & 4095, h = col >> 5, d = col & 31;
            dst[((size_t)(b * 8 + h) * 4096 + n) * 32 + d] = val;
          }
        }
      }
    }
  }
}

// ---------- MFMA flash attention v12: 8-wave block, half-KV per wave-group ----
// Waves 0-3 process KV chunks 0-31, waves 4-7 chunks 32-63, same 64 l-rows.
// Grid (32,16) x 512 threads = 2 blocks/CU x 8 waves = 16 waves/CU (attn10's
// residency — fixes attn11's 8-wave occupancy regression) while KEEPING the
// combine-kernel elimination: one end-of-kernel __syncthreads passes half-1's
// acc/denominator through LDS; half-0 divides and writes aoh/aol directly.
// Main loop is barrier-free per-wave (direct global->reg K/V, swizzled ps).
__global__ __launch_bounds__(512, 4) void attn12(const unsigned short* __restrict__ qbuf,
    const unsigned short* __restrict__ khb, const unsigned short* __restrict__ vfrag,
    const float* __restrict__ ksum, const float* __restrict__ kss,
    const float* __restrict__ vcs,
    unsigned short* __restrict__ aoh, unsigned short* __restrict__ aol)
{
  const int bh = blockIdx.x, b = bh >> 3, h = bh & 7;
  const int lsuper = blockIdx.y;
  const int tid = threadIdx.x, w = tid >> 6, lane = tid & 63;
  const int half = w >> 2, wsub = w & 3;
  const int quad = lane >> 4, l15 = lane & 15;

  __shared__ unsigned short ps[8][16][64];   // [wave][row][kappa], XOR-swizzled; 16KB
  __shared__ float comb[4][16][32];          // half-1 acc hand-off; 8KB
  __shared__ float combD[4][16];             // half-1 denominators

  // Q A-frag with krstd * (1/16) * log2(e) folded in (softmax base-2)
  bf16x8 qa;
  {
    float fold[8];
    const int ch = bh * 32 + quad * 8;
#pragma unroll
    for (int j = 0; j < 8; ++j) {
      float m = ksum[ch + j] * (1.f / 4096.f);
      float var = kss[ch + j] * (1.f / 4096.f) - m * m;
      fold[j] = rsqrtf(var + 1e-5f) * (0.0625f * 1.44269504f);
    }
    int l = lsuper * 64 + wsub * 16 + l15;
    bf16x8 qr = *(const bf16x8*)(qbuf + ((size_t)(b * NL + l)) * 256 + h * 32 + quad * 8);
    const unsigned short* qq = (const unsigned short*)&qr;
    unsigned short tmp[8];
#pragma unroll
    for (int j = 0; j < 8; ++j) tmp[j] = f2b(b2f(qq[j]) * fold[j]);
    qa = *(const bf16x8*)tmp;
  }

  float drow[4] = {0.f, 0.f, 0.f, 0.f};
  f32x4 acc[2];
  acc[0] = (f32x4){0.f,0.f,0.f,0.f};
  acc[1] = (f32x4){0.f,0.f,0.f,0.f};

  // per-lane global fragment addresses; this wave-group's chunks start at c0
  const int c0 = half * 32;
  const unsigned short* kl = khb + (size_t)bh * 131072 + (size_t)c0 * 2048
                             + l15 * 32 + quad * 8;
  const unsigned short* vl = vfrag + (size_t)bh * 131072 + (size_t)c0 * 2048
                             + lane * 8;

  unsigned short* psw = &ps[w][0][0];        // row stride 64 ushorts
  const unsigned rdswz = (unsigned)((l15 & 7) << 4);

  for (int c = 0; c < 32; ++c) {
    bf16x8 kb[4], vb[4];
#pragma unroll
    for (int t = 0; t < 4; ++t)
      kb[t] = *(const bf16x8*)(kl + c * 2048 + t * 512);
#pragma unroll
    for (int i = 0; i < 4; ++i)
      vb[i] = *(const bf16x8*)(vl + c * 2048 + i * 512);

    const f32x4 z = (f32x4){0.f,0.f,0.f,0.f};
    f32x4 sv[4];
    __builtin_amdgcn_s_setprio(1);
#pragma unroll
    for (int t = 0; t < 4; ++t) sv[t] = MFMA16(qa, kb[t], z, 0, 0, 0);
    __builtin_amdgcn_s_setprio(0);
#pragma unroll
    for (int r = 0; r < 4; ++r) {
      // e_t for col l15+16t == kappa 4*l15+t; centered P (x-1), RNE pack
      float x0 = __ocml_native_exp2_f32(sv[0][r]);
      float x1 = __ocml_native_exp2_f32(sv[1][r]);
      float x2 = __ocml_native_exp2_f32(sv[2][r]);
      float x3 = __ocml_native_exp2_f32(sv[3][r]);
      drow[r] += (x0 + x1) + (x2 + x3);
      unsigned pk0, pk1;
      asm("v_cvt_pk_bf16_f32 %0, %1, %2" : "=v"(pk0) : "v"(x0 - 1.0f), "v"(x1 - 1.0f));
      asm("v_cvt_pk_bf16_f32 %0, %1, %2" : "=v"(pk1) : "v"(x2 - 1.0f), "v"(x3 - 1.0f));
      const int row = quad * 4 + r;
      unsigned off = (unsigned)((l15 * 8) ^ ((row & 7) << 4));   // XOR swizzle
      uint2 pk; pk.x = pk0; pk.y = pk1;
      *(uint2*)((char*)(psw + row * 64) + off) = pk;
    }
    asm volatile("s_waitcnt lgkmcnt(0)" ::: "memory");   // this wave's P visible
    __builtin_amdgcn_s_setprio(1);
#pragma unroll
    for (int kh2 = 0; kh2 < 2; ++kh2) {
      unsigned off = (unsigned)((kh2 * 64 + quad * 16) ^ rdswz);
      bf16x8 pa = *(const bf16x8*)((const char*)(psw + l15 * 64) + off);
      acc[0] = MFMA16(pa, vb[kh2 * 2 + 0], acc[0], 0, 0, 0);
      acc[1] = MFMA16(pa, vb[kh2 * 2 + 1], acc[1], 0, 0, 0);
    }
    __builtin_amdgcn_s_setprio(0);
  }

  // centered-P correction: this half's column-sum of V (4 eighth-sums)
  float cs0 = 0.f, cs1 = 0.f;
#pragma unroll
  for (int s = 0; s < 4; ++s) {
    int seg = half * 4 + s;
    cs0 += vcs[seg * 1024 + bh * 32 + l15];
    cs1 += vcs[seg * 1024 + bh * 32 + 16 + l15];
  }

  // per-wave denominator reduce + cs fold
  float svv[4];
#pragma unroll
  for (int r = 0; r < 4; ++r) {
    float sv = drow[r];
    sv += __shfl_xor(sv, 1, 16);
    sv += __shfl_xor(sv, 2, 16);
    sv += __shfl_xor(sv, 4, 16);
    sv += __shfl_xor(sv, 8, 16);
    svv[r] = sv;
    acc[0][r] += cs0;
    acc[1][r] += cs1;
  }

  if (half == 1) {
#pragma unroll
    for (int r = 0; r < 4; ++r) {
      int row16 = quad * 4 + r;
      comb[wsub][row16][l15]      = acc[0][r];
      comb[wsub][row16][16 + l15] = acc[1][r];
      if (l15 == 0) combD[wsub][row16] = svv[r];
    }
  }
  __syncthreads();
  if (half == 0) {
#pragma unroll
    for (int r = 0; r < 4; ++r) {
      int row16 = quad * 4 + r;
      float d  = svv[r] + combD[wsub][row16];
      float o0 = (acc[0][r] + comb[wsub][row16][l15]) / d;
      float o1 = (acc[1][r] + comb[wsub][row16][16 + l15]) / d;
      int l = lsuper * 64 + wsub * 16 + row16;
      size_t idx = ((size_t)(b * NL) + l) * 256 + h * 32;
      unsigned short h0s = f2b(o0);
      unsigned short h1s = f2b(o1);
      aoh[idx + l15]      = h0s;
      aol[idx + l15]      = f2b(o0 - b2f(h0s));
      aoh[idx + 16 + l15] = h1s;
      aol[idx + 16 + l15] = f2b(o1 - b2f(h1s));
    }
  }
}

// ---------- proj GEMM via MFMA hi/lo (3 passes), K=256, fused IN stats ----------
// double-buffered via global_load_lds (R6 form — measured keeper)
__global__ __launch_bounds__(256) void gemm_proj(
    const unsigned short* __restrict__ aoh, const unsigned short* __restrict__ aol,
    const unsigned short* __restrict__ wwh, const unsigned short* __restrict__ wwl,
    const float* __restrict__ bw, float* __restrict__ pj,
    float* __restrict__ psum, float* __restrict__ psq)
{
  __shared__ unsigned short As[2][2048];
  __shared__ unsigned short Bs[2][2048];
  const int bm = blockIdx.x * 64, bn = blockIdx.y * 64;
  const int tid = threadIdx.x, w = tid >> 6, lane = tid & 63;
  const int quad = lane >> 4, l15 = lane & 15;
  const int wr = w >> 1, wc = w & 1;
  const int arow = tid >> 2, apiece = (tid & 3) * 8;

  f32x4 acc[2][2];
#pragma unroll
  for (int i = 0; i < 2; ++i)
#pragma unroll
    for (int j = 0; j < 2; ++j) acc[i][j] = (f32x4){0.f, 0.f, 0.f, 0.f};

  // it = pair*8 + kt; A = pair==1 ? aol : aoh; B = pair==2 ? wwl : wwh
  async_load16(aoh + (size_t)(bm + arow) * 256 + apiece, &As[0][tid * 8]);
  async_load16(wwh + (size_t)(bn + arow) * 256 + apiece, &Bs[0][tid * 8]);

  for (int it = 0; it < 24; ++it) {
    const int cur = it & 1;
    __syncthreads();                       // buf[cur] DMA complete
    if (it < 23) {
      int nx = it + 1;
      int p = nx >> 3;
      const unsigned short* An = (p == 1) ? aol : aoh;
      const unsigned short* Bm = (p == 2) ? wwl : wwh;
      int k0 = (nx & 7) * 32;
      async_load16(An + (size_t)(bm + arow) * 256 + k0 + apiece, &As[cur ^ 1][tid * 8]);
      async_load16(Bm + (size_t)(bn + arow) * 256 + k0 + apiece, &Bs[cur ^ 1][tid * 8]);
    }
    bf16x8 af[2], bf[2];
#pragma unroll
    for (int fr = 0; fr < 2; ++fr)
      af[fr] = *(const bf16x8*)&As[cur][(wr * 32 + fr * 16 + l15) * 32 + quad * 8];
#pragma unroll
    for (int fc = 0; fc < 2; ++fc)
      bf[fc] = *(const bf16x8*)&Bs[cur][(wc * 32 + fc * 16 + l15) * 32 + quad * 8];
#pragma unroll
    for (int fr = 0; fr < 2; ++fr)
#pragma unroll
      for (int fc = 0; fc < 2; ++fc)
        acc[fr][fc] = MFMA16(af[fr], bf[fc], acc[fr][fc], 0, 0, 0);
  }

  const int b = bm >> 10;
#pragma unroll
  for (int fr = 0; fr < 2; ++fr)
#pragma unroll
    for (int fc = 0; fc < 2; ++fc) {
      int col = bn + wc * 32 + fc * 16 + l15;
      float bb = bw[col];
      float s = 0.f, ssq = 0.f;
#pragma unroll
      for (int r = 0; r < 4; ++r) {
        int row = bm + wr * 32 + fr * 16 + quad * 4 + r;
        float v = acc[fr][fc][r] + bb;
        pj[(size_t)row * 256 + col] = v;
        s += v; ssq += v * v;
      }
      s += __shfl_xor(s, 16); s += __shfl_xor(s, 32);
      ssq += __shfl_xor(ssq, 16); ssq += __shfl_xor(ssq, 32);
      if (quad == 0) {
        atomicAdd(&psum[b * 256 + col], s);
        atomicAdd(&psq[b * 256 + col], ssq);
      }
    }
}

// ---------- final IN normalize ----------
__global__ __launch_bounds__(256) void final_out(const float* __restrict__ proj,
    const float* __restrict__ psum, const float* __restrict__ psq,
    float* __restrict__ out)
{
  const int b = blockIdx.x, o = threadIdx.x;
  const int l1 = blockIdx.y * 16;
  const float m = psum[b * 256 + o] * (1.f / 1024.f);
  const float r = rsqrtf(psq[b * 256 + o] * (1.f / 1024.f) - m * m + 1e-5f);
  for (int i = 0; i < 16; ++i) {
    size_t idx = ((size_t)(b * NL + l1 + i)) * 256 + o;
    out[idx] = (proj[idx] - m) * r;
  }
}

extern "C" void kernel_launch(void* const* d_in, const int* in_sizes, int n_in,
                              void* d_out, int out_size, void* d_ws, size_t ws_size,
                              hipStream_t stream)
{
  const float* l  = (const float*)d_in[0];
  const float* x  = (const float*)d_in[1];
  const float* Wq = (const float*)d_in[2];
  const float* bq = (const float*)d_in[3];
  const float* Wk = (const float*)d_in[4];
  const float* bk = (const float*)d_in[5];
  const float* Wv = (const float*)d_in[6];
  const float* bv = (const float*)d_in[7];
  const float* Ww = (const float*)d_in[8];
  const float* bw = (const float*)d_in[9];
  float* out = (float*)d_out;

  unsigned short* up = (unsigned short*)d_ws;
  unsigned short* xbf   = up;                         // 8,388,608
  unsigned short* lbf   = xbf   + 8388608;            // 2,097,152
  unsigned short* wkb   = lbf   + 2097152;            // 131,072
  unsigned short* wvb   = wkb   + 131072;
  unsigned short* wqb   = wvb   + 131072;
  unsigned short* qbuf  = wqb   + 131072;             // 1,048,576
  unsigned short* khb   = qbuf  + 1048576;            // 4,194,304
  unsigned short* vhb   = khb   + 4194304;            // (unused slot, kept for layout)
  unsigned short* vfrag = vhb   + 4194304;
  unsigned short* aoh   = vfrag + 4194304;            // 1,048,576
  unsigned short* aol   = aoh   + 1048576;
  unsigned short* wwh   = aol   + 1048576;            // 65,536
  unsigned short* wwl   = wwh   + 65536;
  float* F     = (float*)((char*)d_ws + 53477376);
  float* ksum  = F;                                   // 1024  } zeroed by convall
  float* kss   = F + 1024;                            // 1024  }
  float* vcs   = F + 2048;                            // 8192  }
  float* psum  = F + 10240;                           // 1024  }
  float* psq   = F + 11264;                           // 1024  }
  float* pj    = F + 15360;                           // 1,048,576

  dim3 blk(256);
  convall<<<10764, blk, 0, stream>>>(x, l, Wk, Wv, Wq, Ww, xbf, lbf,
                                     wkb, wvb, wqb, wwh, wwl, F);
  gemm128<<<576, blk, 0, stream>>>(xbf, lbf, wkb, wvb, wqb, bk, bv, bq,
                                   khb, vfrag, qbuf, ksum, kss, vcs);
  attn12<<<dim3(32, 16), dim3(512), 0, stream>>>(qbuf, khb, vfrag, ksum, kss, vcs,
                                                 aoh, aol);
  gemm_proj<<<dim3(64, 4), blk, 0, stream>>>(aoh, aol, wwh, wwl, bw, pj, psum, psq);
  final_out<<<dim3(4, 64), blk, 0, stream>>>(pj, psum, psq, out);
}

// Round 8
// 169.950 us; speedup vs baseline: 1.0749x; 1.0749x over previous
//
#include <hip/hip_runtime.h>

constexpr int Bn = 4, NL = 1024, HWn = 4096, NH = 8;

typedef __attribute__((ext_vector_type(8))) short bf16x8;
typedef __attribute__((ext_vector_type(4))) float f32x4;
#define MFMA16 __builtin_amdgcn_mfma_f32_16x16x32_bf16

extern "C" __device__ float __ocml_native_exp2_f32(float);

__device__ __forceinline__ float b2f(unsigned short u) {
  union { unsigned int i; float f; } x; x.i = ((unsigned int)u) << 16; return x.f;
}
__device__ __forceinline__ unsigned short f2b(float f) {
  union { float f; unsigned int i; } x; x.f = f;
  unsigned int r = x.i + 0x7fffu + ((x.i >> 16) & 1u);   // RNE
  return (unsigned short)(r >> 16);
}

// async global->LDS DMA, 16B per lane; LDS dst = readfirstlane(l) + lane*16
__device__ __forceinline__ void async_load16(const unsigned short* g, unsigned short* l) {
  __builtin_amdgcn_global_load_lds(
      (const __attribute__((address_space(1))) unsigned int*)g,
      (__attribute__((address_space(3))) unsigned int*)l, 16, 0, 0);
}

// ---------- ALL input conversions + stats-buffer zeroing in one launch ----------
__global__ __launch_bounds__(256) void convall(const float* __restrict__ x,
    const float* __restrict__ l,
    const float* __restrict__ Wk, const float* __restrict__ Wv,
    const float* __restrict__ Wq, const float* __restrict__ Ww,
    unsigned short* __restrict__ xbf, unsigned short* __restrict__ lbf,
    unsigned short* __restrict__ wkb, unsigned short* __restrict__ wvb,
    unsigned short* __restrict__ wqb,
    unsigned short* __restrict__ wwh, unsigned short* __restrict__ wwl,
    float* __restrict__ Fz)
{
  const int id = blockIdx.x, tid = threadIdx.x;
  if (id < 8192) {
    int i = (id * 256 + tid) * 4;
    float4 v = *(const float4*)(x + i);
    ushort4 o; o.x = f2b(v.x); o.y = f2b(v.y); o.z = f2b(v.z); o.w = f2b(v.w);
    *(ushort4*)(xbf + i) = o;
  } else if (id < 10240) {
    int i = ((id - 8192) * 256 + tid) * 4;
    float4 v = *(const float4*)(l + i);
    ushort4 o; o.x = f2b(v.x); o.y = f2b(v.y); o.z = f2b(v.z); o.w = f2b(v.w);
    *(ushort4*)(lbf + i) = o;
  } else if (id < 10752) {
    int sub = id - 10240;
    int y = sub >> 7, bx = sub & 127;
    int i = (bx * 256 + tid) * 4;
    if (y == 3) {
      if (i >= 65536) return;
      float4 v = *(const float4*)(Ww + i);
      ushort4 hi, lo;
      hi.x = f2b(v.x); lo.x = f2b(v.x - b2f(hi.x));
      hi.y = f2b(v.y); lo.y = f2b(v.y - b2f(hi.y));
      hi.z = f2b(v.z); lo.z = f2b(v.z - b2f(hi.z));
      hi.w = f2b(v.w); lo.w = f2b(v.w - b2f(hi.w));
      *(ushort4*)(wwh + i) = hi;
      *(ushort4*)(wwl + i) = lo;
      return;
    }
    const float* src = y == 0 ? Wk : (y == 1 ? Wv : Wq);
    unsigned short* dst = y == 0 ? wkb : (y == 1 ? wvb : wqb);
    float4 v = *(const float4*)(src + i);
    ushort4 o; o.x = f2b(v.x); o.y = f2b(v.y); o.z = f2b(v.z); o.w = f2b(v.w);
    *(ushort4*)(dst + i) = o;
  } else {
    int i = (id - 10752) * 1024 + tid * 4;
    *(float4*)(Fz + i) = (float4){0.f, 0.f, 0.f, 0.f};
  }
}

// ---------- unified 128x128 MFMA GEMM, K=512, dbuf LDS + global_load_lds ----------
// V-mode: vfrag-layout store staged through LDS -> coalesced bf16x8 stores.
// K-stats / V-colsum fusion. (R6/R7 measured keeper.)
__global__ __launch_bounds__(256, 3) void gemm128(
    const unsigned short* __restrict__ xbf, const unsigned short* __restrict__ lbf,
    const unsigned short* __restrict__ wkb, const unsigned short* __restrict__ wvb,
    const unsigned short* __restrict__ wqb,
    const float* __restrict__ bk, const float* __restrict__ bv, const float* __restrict__ bq,
    unsigned short* __restrict__ khb, unsigned short* __restrict__ vfrag,
    unsigned short* __restrict__ qbuf,
    float* __restrict__ ksum, float* __restrict__ kss, float* __restrict__ vcs)
{
  __shared__ unsigned short sh[16384];        // As[2][4096] | Bs[2][4096]; reused as V-stage
  unsigned short* As0 = sh;
  unsigned short* Bs0 = sh + 8192;
  const int id = blockIdx.x;
  const int mode = id < 256 ? 0 : (id < 512 ? 1 : 2);   // 0=K 1=V 2=Q
  const int local = id - (mode == 0 ? 0 : (mode == 1 ? 256 : 512));
  const int rb = local >> 1, cb = local & 1;
  const int m0 = rb * 128, n0 = cb * 128;
  const unsigned short* A = (mode == 2) ? lbf : xbf;
  const unsigned short* W = (mode == 0) ? wkb : (mode == 1 ? wvb : wqb);
  const float* bias = (mode == 0) ? bk : (mode == 1 ? bv : bq);

  const int tid = threadIdx.x, w = tid >> 6, lane = tid & 63;
  const int quad = lane >> 4, l15 = lane & 15;
  const int wr = w >> 1, wc = w & 1;

  const int p0 = tid, p1 = tid + 256;
  const int am0 = p0 >> 2, ak0 = (p0 & 3) * 8;
  const int am1 = p1 >> 2, ak1 = (p1 & 3) * 8;

  f32x4 acc[4][4];
#pragma unroll
  for (int i = 0; i < 4; ++i)
#pragma unroll
    for (int j = 0; j < 4; ++j) acc[i][j] = (f32x4){0.f, 0.f, 0.f, 0.f};

  // prologue: async-stage kt=0 into buf 0
  async_load16(A + (size_t)(m0 + am0) * 512 + ak0, &As0[p0 * 8]);
  async_load16(A + (size_t)(m0 + am1) * 512 + ak1, &As0[p1 * 8]);
  async_load16(W + (size_t)(n0 + am0) * 512 + ak0, &Bs0[p0 * 8]);
  async_load16(W + (size_t)(n0 + am1) * 512 + ak1, &Bs0[p1 * 8]);

  for (int kt = 0; kt < 16; ++kt) {
    const int cur = kt & 1;
    __syncthreads();                       // buf[cur] DMA complete (vmcnt drained)
    if (kt < 15) {                         // prefetch kt+1 into the other buffer
      int k0 = (kt + 1) * 32;
      int nx = (cur ^ 1) * 4096;
      async_load16(A + (size_t)(m0 + am0) * 512 + k0 + ak0, &As0[nx + p0 * 8]);
      async_load16(A + (size_t)(m0 + am1) * 512 + k0 + ak1, &As0[nx + p1 * 8]);
      async_load16(W + (size_t)(n0 + am0) * 512 + k0 + ak0, &Bs0[nx + p0 * 8]);
      async_load16(W + (size_t)(n0 + am1) * 512 + k0 + ak1, &Bs0[nx + p1 * 8]);
    }
    bf16x8 af[4], bf[4];
#pragma unroll
    for (int fr = 0; fr < 4; ++fr)
      af[fr] = *(const bf16x8*)&As0[cur * 4096 + (wr * 64 + fr * 16 + l15) * 32 + quad * 8];
#pragma unroll
    for (int fc = 0; fc < 4; ++fc)
      bf[fc] = *(const bf16x8*)&Bs0[cur * 4096 + (wc * 64 + fc * 16 + l15) * 32 + quad * 8];
#pragma unroll
    for (int fr = 0; fr < 4; ++fr)
#pragma unroll
      for (int fc = 0; fc < 4; ++fc)
        acc[fr][fc] = MFMA16(af[fr], bf[fc], acc[fr][fc], 0, 0, 0);
  }

  float bb[4];
#pragma unroll
  for (int fc = 0; fc < 4; ++fc) bb[fc] = bias[n0 + wc * 64 + fc * 16 + l15];

  // fused K/V instance-norm & colsum stats (f32 pre-round; error ~1e-5 rel)
  if (mode != 2) {
    const int b = m0 >> 12;
    const int seg = (m0 & 4095) >> 9;
#pragma unroll
    for (int fc = 0; fc < 4; ++fc) {
      float s = 0.f, ssq = 0.f;
#pragma unroll
      for (int fr = 0; fr < 4; ++fr)
#pragma unroll
        for (int r = 0; r < 4; ++r) {
          float v = acc[fr][fc][r] + bb[fc];
          s += v; ssq += v * v;
        }
      s += __shfl_xor(s, 16); s += __shfl_xor(s, 32);
      if (mode == 0) {
        ssq += __shfl_xor(ssq, 16); ssq += __shfl_xor(ssq, 32);
        if (quad == 0) {
          int col = n0 + wc * 64 + fc * 16 + l15;
          atomicAdd(&ksum[b * 256 + col], s);
          atomicAdd(&kss[b * 256 + col], ssq);
        }
      } else if (quad == 0) {
        int col = n0 + wc * 64 + fc * 16 + l15;
        atomicAdd(&vcs[seg * 1024 + b * 256 + col], s);
      }
    }
  }

  if (mode == 1) {
    // stage block's V-tile in LDS (vfrag-local layout), then coalesced stores
    __syncthreads();                       // all waves done reading As/Bs
#pragma unroll
    for (int fc = 0; fc < 4; ++fc) {
      const int ls = wr * 4 + wc * 2 + ((fc * 16 + l15) >> 5);
      const int dvt = fc & 1;
#pragma unroll
      for (int fr = 0; fr < 4; ++fr) {
#pragma unroll
        for (int r = 0; r < 4; ++r) {
          int kappa = 4 * (quad * 4 + r) + fr;
          int kh2 = kappa >> 5, lq = (kappa >> 3) & 3, j = kappa & 7;
          sh[ls * 2048 + kh2 * 1024 + dvt * 512 + lq * 128 + l15 * 8 + j] =
              f2b(acc[fr][fc][r] + bb[fc]);
        }
      }
    }
    __syncthreads();
    const int b2 = m0 >> 12, h0 = cb * 4, seg64b = (m0 & 4095) >> 6;
#pragma unroll
    for (int i = 0; i < 8; ++i) {
      int p = i * 256 + tid;
      int ls = p >> 8, off8 = (p & 255) * 8;
      int dh = ls & 3, wr2 = ls >> 2;
      size_t dst = ((size_t)((b2 * 8 + h0 + dh) * 64) + seg64b + wr2) * 2048 + off8;
      *(bf16x8*)(vfrag + dst) = *(const bf16x8*)&sh[ls * 2048 + off8];
    }
  } else {
    unsigned short* dst = (mode == 0) ? khb : qbuf;
#pragma unroll
    for (int fr = 0; fr < 4; ++fr) {
#pragma unroll
      for (int fc = 0; fc < 4; ++fc) {
        int col = n0 + wc * 64 + fc * 16 + l15;
#pragma unroll
        for (int r = 0; r < 4; ++r) {
          int row = m0 + wr * 64 + fr * 16 + quad * 4 + r;
          unsigned short val = f2b(acc[fr][fc][r] + bb[fc]);
          if (mode == 2) {
            dst[(size_t)row * 256 + col] = val;
          } else {
            int b = row >> 12, n = row & 4095, h = col >> 5, d = col & 31;
            dst[((size_t)(b * 8 + h) * 4096 + n) * 32 + d] = val;
          }
        }
      }
    }
  }
}

// ---------- MFMA flash attention v10 (R5 best-measured form) ----------
// Quarter-split KV (grid z=4), lf=2 (32 l-rows/wave -> 0.5 K/V loads per MFMA,
// the reuse ratio attn11/12 lost). Barrier-free; direct global->reg K/V loads;
// swizzled ps; cvt_pk pack; setprio. Writes po/pd partials (combine4 follows).
// grid (32, 8, 4) = (bh, lsuper, quarter); block 256; 4 blocks/CU.
__global__ __launch_bounds__(256, 4) void attn10(const unsigned short* __restrict__ qbuf,
    const unsigned short* __restrict__ khb, const unsigned short* __restrict__ vfrag,
    const float* __restrict__ ksum, const float* __restrict__ kss,
    const float* __restrict__ vcs,
    float* __restrict__ po, float* __restrict__ pd)
{
  const int bh = blockIdx.x, b = bh >> 3, h = bh & 7;
  const int lsuper = blockIdx.y, quarter = blockIdx.z;
  const int tid = threadIdx.x, w = tid >> 6, lane = tid & 63;
  const int quad = lane >> 4, l15 = lane & 15;

  __shared__ unsigned short ps[4][2][16][64];   // [wave][lf][row][kappa], XOR-swizzled

  // Q A-frags with krstd * (1/16) * log2(e) folded in (softmax base-2)
  bf16x8 qa[2];
  {
    float fold[8];
    const int ch = bh * 32 + quad * 8;
#pragma unroll
    for (int j = 0; j < 8; ++j) {
      float m = ksum[ch + j] * (1.f / 4096.f);
      float var = kss[ch + j] * (1.f / 4096.f) - m * m;
      fold[j] = rsqrtf(var + 1e-5f) * (0.0625f * 1.44269504f);
    }
#pragma unroll
    for (int lf = 0; lf < 2; ++lf) {
      int l = lsuper * 128 + w * 32 + lf * 16 + l15;
      bf16x8 qr = *(const bf16x8*)(qbuf + ((size_t)(b * NL + l)) * 256 + h * 32 + quad * 8);
      const unsigned short* qq = (const unsigned short*)&qr;
      unsigned short tmp[8];
#pragma unroll
      for (int j = 0; j < 8; ++j) tmp[j] = f2b(b2f(qq[j]) * fold[j]);
      qa[lf] = *(const bf16x8*)tmp;
    }
  }

  float drow[2][4];
  f32x4 acc[2][2];
#pragma unroll
  for (int lf = 0; lf < 2; ++lf) {
#pragma unroll
    for (int r = 0; r < 4; ++r) drow[lf][r] = 0.f;
    acc[lf][0] = (f32x4){0.f,0.f,0.f,0.f};
    acc[lf][1] = (f32x4){0.f,0.f,0.f,0.f};
  }

  // per-lane global fragment addresses (both perfectly coalesced: 64 x 16B)
  const unsigned short* kl = khb + (size_t)bh * 131072 + (size_t)quarter * 32768
                             + l15 * 32 + quad * 8;
  const unsigned short* vl = vfrag + (size_t)bh * 131072 + (size_t)quarter * 32768
                             + lane * 8;

  unsigned short* psw = &ps[w][0][0][0];        // lf stride 1024, row stride 64 (ushorts)
  const unsigned rdswz = (unsigned)((l15 & 7) << 4);

  for (int c = 0; c < 16; ++c) {
    bf16x8 kb[4], vb[4];
#pragma unroll
    for (int t = 0; t < 4; ++t)
      kb[t] = *(const bf16x8*)(kl + c * 2048 + t * 512);
#pragma unroll
    for (int i = 0; i < 4; ++i)
      vb[i] = *(const bf16x8*)(vl + c * 2048 + i * 512);

    const f32x4 z = (f32x4){0.f,0.f,0.f,0.f};
#pragma unroll
    for (int lf = 0; lf < 2; ++lf) {
      f32x4 sv[4];
      __builtin_amdgcn_s_setprio(1);
#pragma unroll
      for (int t = 0; t < 4; ++t) sv[t] = MFMA16(qa[lf], kb[t], z, 0, 0, 0);
      __builtin_amdgcn_s_setprio(0);
#pragma unroll
      for (int r = 0; r < 4; ++r) {
        // e_t for col l15+16t == kappa 4*l15+t; centered P (x-1), RNE pack
        float x0 = __ocml_native_exp2_f32(sv[0][r]);
        float x1 = __ocml_native_exp2_f32(sv[1][r]);
        float x2 = __ocml_native_exp2_f32(sv[2][r]);
        float x3 = __ocml_native_exp2_f32(sv[3][r]);
        drow[lf][r] += (x0 + x1) + (x2 + x3);
        unsigned pk0, pk1;
        asm("v_cvt_pk_bf16_f32 %0, %1, %2" : "=v"(pk0) : "v"(x0 - 1.0f), "v"(x1 - 1.0f));
        asm("v_cvt_pk_bf16_f32 %0, %1, %2" : "=v"(pk1) : "v"(x2 - 1.0f), "v"(x3 - 1.0f));
        const int row = quad * 4 + r;
        unsigned off = (unsigned)((l15 * 8) ^ ((row & 7) << 4));   // XOR swizzle
        uint2 pk; pk.x = pk0; pk.y = pk1;
        *(uint2*)((char*)(psw + lf * 1024 + row * 64) + off) = pk;
      }
      asm volatile("s_waitcnt lgkmcnt(0)" ::: "memory");   // this wave's P visible
      __builtin_amdgcn_s_setprio(1);
#pragma unroll
      for (int kh2 = 0; kh2 < 2; ++kh2) {
        unsigned off = (unsigned)((kh2 * 64 + quad * 16) ^ rdswz);
        bf16x8 pa = *(const bf16x8*)((const char*)(psw + lf * 1024 + l15 * 64) + off);
        acc[lf][0] = MFMA16(pa, vb[kh2 * 2 + 0], acc[lf][0], 0, 0, 0);
        acc[lf][1] = MFMA16(pa, vb[kh2 * 2 + 1], acc[lf][1], 0, 0, 0);
      }
      __builtin_amdgcn_s_setprio(0);
    }
  }

  // centered-P correction: quarter column-sum of V = two eighth-sums
  const float* vc0 = vcs + (quarter * 2) * 1024 + bh * 32;
  const float* vc1 = vc0 + 1024;
  float cs0 = vc0[l15] + vc1[l15];
  float cs1 = vc0[16 + l15] + vc1[16 + l15];
#pragma unroll
  for (int lf = 0; lf < 2; ++lf)
#pragma unroll
    for (int r = 0; r < 4; ++r) {
      acc[lf][0][r] += cs0;
      acc[lf][1][r] += cs1;
    }

  // write partials; po col layout interleaved: col' = l15*2 + dvt
  const size_t PDo = (size_t)quarter * 32768 + (size_t)bh * 1024;
#pragma unroll
  for (int lf = 0; lf < 2; ++lf) {
#pragma unroll
    for (int r = 0; r < 4; ++r) {
      float sv = drow[lf][r];
      sv += __shfl_xor(sv, 1, 16);
      sv += __shfl_xor(sv, 2, 16);
      sv += __shfl_xor(sv, 4, 16);
      sv += __shfl_xor(sv, 8, 16);
      int l = lsuper * 128 + w * 32 + lf * 16 + quad * 4 + r;
      float2 val; val.x = acc[lf][0][r]; val.y = acc[lf][1][r];
      *(float2*)(po + (PDo + l) * 32 + l15 * 2) = val;
      if (l15 == 0) pd[PDo + l] = sv;
    }
  }
}

// ---------- combine 4 n-quarters -> ao hi/lo bf16 ----------
__global__ __launch_bounds__(256) void combine4(const float* __restrict__ po,
    const float* __restrict__ pd, unsigned short* __restrict__ aoh,
    unsigned short* __restrict__ aol)
{
  int gid = blockIdx.x * 256 + threadIdx.x;
  int dv = gid & 31, l = (gid >> 5) & (NL - 1), h = (gid >> 15) & 7, b = gid >> 18;
  int c = ((dv & 15) << 1) | (dv >> 4);     // inverse of interleaved po layout
  size_t r = ((size_t)(b * 8 + h)) * 1024 + l;
  float d = 0.f, o = 0.f;
#pragma unroll
  for (int q = 0; q < 4; ++q) {
    size_t rr = (size_t)q * 32768 + r;
    d += pd[rr];
    o += po[rr * 32 + c];
  }
  o = o / d;
  unsigned short hi = f2b(o);
  size_t idx = ((size_t)(b * NL) + l) * 256 + h * 32 + dv;
  aoh[idx] = hi;
  aol[idx] = f2b(o - b2f(hi));
}

// ---------- proj GEMM via MFMA hi/lo (3 passes), K=256, fused IN stats ----------
// double-buffered via global_load_lds (R6/R7 measured keeper)
__global__ __launch_bounds__(256) void gemm_proj(
    const unsigned short* __restrict__ aoh, const unsigned short* __restrict__ aol,
    const unsigned short* __restrict__ wwh, const unsigned short* __restrict__ wwl,
    const float* __restrict__ bw, float* __restrict__ pj,
    float* __restrict__ psum, float* __restrict__ psq)
{
  __shared__ unsigned short As[2][2048];
  __shared__ unsigned short Bs[2][2048];
  const int bm = blockIdx.x * 64, bn = blockIdx.y * 64;
  const int tid = threadIdx.x, w = tid >> 6, lane = tid & 63;
  const int quad = lane >> 4, l15 = lane & 15;
  const int wr = w >> 1, wc = w & 1;
  const int arow = tid >> 2, apiece = (tid & 3) * 8;

  f32x4 acc[2][2];
#pragma unroll
  for (int i = 0; i < 2; ++i)
#pragma unroll
    for (int j = 0; j < 2; ++j) acc[i][j] = (f32x4){0.f, 0.f, 0.f, 0.f};

  // it = pair*8 + kt; A = pair==1 ? aol : aoh; B = pair==2 ? wwl : wwh
  async_load16(aoh + (size_t)(bm + arow) * 256 + apiece, &As[0][tid * 8]);
  async_load16(wwh + (size_t)(bn + arow) * 256 + apiece, &Bs[0][tid * 8]);

  for (int it = 0; it < 24; ++it) {
    const int cur = it & 1;
    __syncthreads();                       // buf[cur] DMA complete
    if (it < 23) {
      int nx = it + 1;
      int p = nx >> 3;
      const unsigned short* An = (p == 1) ? aol : aoh;
      const unsigned short* Bm = (p == 2) ? wwl : wwh;
      int k0 = (nx & 7) * 32;
      async_load16(An + (size_t)(bm + arow) * 256 + k0 + apiece, &As[cur ^ 1][tid * 8]);
      async_load16(Bm + (size_t)(bn + arow) * 256 + k0 + apiece, &Bs[cur ^ 1][tid * 8]);
    }
    bf16x8 af[2], bf[2];
#pragma unroll
    for (int fr = 0; fr < 2; ++fr)
      af[fr] = *(const bf16x8*)&As[cur][(wr * 32 + fr * 16 + l15) * 32 + quad * 8];
#pragma unroll
    for (int fc = 0; fc < 2; ++fc)
      bf[fc] = *(const bf16x8*)&Bs[cur][(wc * 32 + fc * 16 + l15) * 32 + quad * 8];
#pragma unroll
    for (int fr = 0; fr < 2; ++fr)
#pragma unroll
      for (int fc = 0; fc < 2; ++fc)
        acc[fr][fc] = MFMA16(af[fr], bf[fc], acc[fr][fc], 0, 0, 0);
  }

  const int b = bm >> 10;
#pragma unroll
  for (int fr = 0; fr < 2; ++fr)
#pragma unroll
    for (int fc = 0; fc < 2; ++fc) {
      int col = bn + wc * 32 + fc * 16 + l15;
      float bb = bw[col];
      float s = 0.f, ssq = 0.f;
#pragma unroll
      for (int r = 0; r < 4; ++r) {
        int row = bm + wr * 32 + fr * 16 + quad * 4 + r;
        float v = acc[fr][fc][r] + bb;
        pj[(size_t)row * 256 + col] = v;
        s += v; ssq += v * v;
      }
      s += __shfl_xor(s, 16); s += __shfl_xor(s, 32);
      ssq += __shfl_xor(ssq, 16); ssq += __shfl_xor(ssq, 32);
      if (quad == 0) {
        atomicAdd(&psum[b * 256 + col], s);
        atomicAdd(&psq[b * 256 + col], ssq);
      }
    }
}

// ---------- final IN normalize ----------
__global__ __launch_bounds__(256) void final_out(const float* __restrict__ proj,
    const float* __restrict__ psum, const float* __restrict__ psq,
    float* __restrict__ out)
{
  const int b = blockIdx.x, o = threadIdx.x;
  const int l1 = blockIdx.y * 16;
  const float m = psum[b * 256 + o] * (1.f / 1024.f);
  const float r = rsqrtf(psq[b * 256 + o] * (1.f / 1024.f) - m * m + 1e-5f);
  for (int i = 0; i < 16; ++i) {
    size_t idx = ((size_t)(b * NL + l1 + i)) * 256 + o;
    out[idx] = (proj[idx] - m) * r;
  }
}

extern "C" void kernel_launch(void* const* d_in, const int* in_sizes, int n_in,
                              void* d_out, int out_size, void* d_ws, size_t ws_size,
                              hipStream_t stream)
{
  const float* l  = (const float*)d_in[0];
  const float* x  = (const float*)d_in[1];
  const float* Wq = (const float*)d_in[2];
  const float* bq = (const float*)d_in[3];
  const float* Wk = (const float*)d_in[4];
  const float* bk = (const float*)d_in[5];
  const float* Wv = (const float*)d_in[6];
  const float* bv = (const float*)d_in[7];
  const float* Ww = (const float*)d_in[8];
  const float* bw = (const float*)d_in[9];
  float* out = (float*)d_out;

  unsigned short* up = (unsigned short*)d_ws;
  unsigned short* xbf   = up;                         // 8,388,608
  unsigned short* lbf   = xbf   + 8388608;            // 2,097,152
  unsigned short* wkb   = lbf   + 2097152;            // 131,072
  unsigned short* wvb   = wkb   + 131072;
  unsigned short* wqb   = wvb   + 131072;
  unsigned short* qbuf  = wqb   + 131072;             // 1,048,576
  unsigned short* khb   = qbuf  + 1048576;            // 4,194,304
  unsigned short* vhb   = khb   + 4194304;            // (unused slot, kept for layout)
  unsigned short* vfrag = vhb   + 4194304;
  unsigned short* aoh   = vfrag + 4194304;            // 1,048,576
  unsigned short* aol   = aoh   + 1048576;
  unsigned short* wwh   = aol   + 1048576;            // 65,536
  unsigned short* wwl   = wwh   + 65536;
  float* F     = (float*)((char*)d_ws + 53477376);
  float* ksum  = F;                                   // 1024  } zeroed by convall
  float* kss   = F + 1024;                            // 1024  }
  float* vcs   = F + 2048;                            // 8192  }
  float* psum  = F + 10240;                           // 1024  }
  float* psq   = F + 11264;                           // 1024  }
  float* po    = F + 15360;                           // 4 * 1,048,576
  float* pd    = po + 4194304;                        // 131,072
  float* pj    = po;                                  // alias: po dead after combine4

  dim3 blk(256);
  convall<<<10764, blk, 0, stream>>>(x, l, Wk, Wv, Wq, Ww, xbf, lbf,
                                     wkb, wvb, wqb, wwh, wwl, F);
  gemm128<<<576, blk, 0, stream>>>(xbf, lbf, wkb, wvb, wqb, bk, bv, bq,
                                   khb, vfrag, qbuf, ksum, kss, vcs);
  attn10<<<dim3(32, 8, 4), blk, 0, stream>>>(qbuf, khb, vfrag, ksum, kss, vcs, po, pd);
  combine4<<<4096, blk, 0, stream>>>(po, pd, aoh, aol);
  gemm_proj<<<dim3(64, 4), blk, 0, stream>>>(aoh, aol, wwh, wwl, bw, pj, psum, psq);
  final_out<<<dim3(4, 64), blk, 0, stream>>>(pj, psum, psq, out);
}